// Round 8
// baseline (501.848 us; speedup 1.0000x reference)
//
#include <hip/hip_runtime.h>

#define HIDDEN 256
#define NGRAPH 1024
#define EPS 1e-6f
#define LDS_SWEEPS 2          // sweeps staged in LDS   (rows 0..127, 128 KB)
#define REG_SWEEPS 5          // sweeps staged in VGPRs (rows 128..447, 160 VGPR/wave)
#define STAGE_SWEEPS (LDS_SWEEPS + REG_SWEEPS)

typedef float f32x4 __attribute__((ext_vector_type(4)));

__device__ __forceinline__ float ssum(const f32x4 v) {
    return v.x * v.x + v.y * v.y + v.z * v.z + v.w * v.w;
}

// One block per graph (batch sorted => graph g owns contiguous rows [start,end)).
// Phase A: stream the slab once. Rows 0..127 -> LDS, rows 128..447 -> registers
//          (both loaded NON-TEMPORALLY: they never need L3). Rows 448+ loaded
//          cacheable - they are the only L3-allocating stream, so each line's
//          reuse window (~256*(1-f) MB aggregate) fits the 256 MB L3.
// Phase B: reverse sweep order (best-recency lines first). Staged rows come
//          from LDS/VGPRs; the rest via NT loads (dead after use). All output
//          written with NT stores so the 1 GB write stream evicts nothing.
//
// 128 KB static LDS forces 1 block/CU: 256 resident blocks x ~1 MB slab ~= L3.
// Sweep->wave mapping is identical in both phases, so each wave reads back its
// own LDS/register stage (no barrier beyond the reduce's syncthreads).
__global__ __launch_bounds__(512, 2) void k_fused(
    const float* __restrict__ x, const int* __restrict__ batch,
    const float* __restrict__ w, float* __restrict__ out, int n_nodes) {

    __shared__ float smem[LDS_SWEEPS * 64 * HIDDEN + 8];   // 128 KB + reduce scratch

    const int g    = (int)blockIdx.x;
    const int tid  = (int)threadIdx.x;
    const int lane = tid & 63;
    const int wid  = tid >> 6;      // 0..7

    // Binary-search graph bounds (wave-uniform broadcast loads, ~40 total).
    int lo = 0, hi = n_nodes;
    while (lo < hi) { int m = (lo + hi) >> 1; if (batch[m] < g) lo = m + 1; else hi = m; }
    const int start = lo;
    int lo2 = start, hi2 = n_nodes;
    while (lo2 < hi2) { int m = (lo2 + hi2) >> 1; if (batch[m] < g + 1) lo2 = m + 1; else hi2 = m; }
    const int count = lo2 - start;
    if (count <= 0) return;         // block-uniform: safe w.r.t. __syncthreads below

    const int nsweep = (count + 63) >> 6;   // 8 waves x 8 rows per sweep

    float acc = 0.0f;
    f32x4 rv[REG_SWEEPS][8];        // statically indexed only (full unroll below)

    // ---- Phase A ----
    // LDS-staged sweeps (NT loads: these lines never need L3).
    #pragma unroll
    for (int s = 0; s < LDS_SWEEPS; ++s) {
        const int base = (s << 6) + (wid << 3);
        if (base + 8 <= count) {
            f32x4 v[8];
            #pragma unroll
            for (int k = 0; k < 8; ++k)
                v[k] = __builtin_nontemporal_load(reinterpret_cast<const f32x4*>(
                    x + (size_t)(start + base + k) * HIDDEN + (size_t)lane * 4));
            #pragma unroll
            for (int k = 0; k < 8; ++k)
                *reinterpret_cast<f32x4*>(&smem[(base + k) * HIDDEN + lane * 4]) = v[k];
            #pragma unroll
            for (int k = 0; k < 8; ++k) acc += ssum(v[k]);
        } else {
            for (int r = base; r < count; ++r)
                acc += ssum(*reinterpret_cast<const f32x4*>(
                    x + (size_t)(start + r) * HIDDEN + (size_t)lane * 4));
        }
    }
    // Register-staged sweeps (NT loads; rv indices compile-time via unroll).
    #pragma unroll
    for (int j = 0; j < REG_SWEEPS; ++j) {
        const int base = ((LDS_SWEEPS + j) << 6) + (wid << 3);
        if (base + 8 <= count) {
            #pragma unroll
            for (int k = 0; k < 8; ++k)
                rv[j][k] = __builtin_nontemporal_load(reinterpret_cast<const f32x4*>(
                    x + (size_t)(start + base + k) * HIDDEN + (size_t)lane * 4));
            #pragma unroll
            for (int k = 0; k < 8; ++k) acc += ssum(rv[j][k]);
        } else {
            for (int r = base; r < count; ++r)
                acc += ssum(*reinterpret_cast<const f32x4*>(
                    x + (size_t)(start + r) * HIDDEN + (size_t)lane * 4));
        }
    }
    // Unstaged sweeps: cacheable loads (the only L3-allocating stream).
    for (int s = STAGE_SWEEPS; s < nsweep; ++s) {
        const int base = (s << 6) + (wid << 3);
        if (base + 8 <= count) {
            f32x4 v[8];
            #pragma unroll
            for (int k = 0; k < 8; ++k)
                v[k] = *reinterpret_cast<const f32x4*>(
                    x + (size_t)(start + base + k) * HIDDEN + (size_t)lane * 4);
            #pragma unroll
            for (int k = 0; k < 8; ++k) acc += ssum(v[k]);
        } else {
            for (int r = base; r < count; ++r)
                acc += ssum(*reinterpret_cast<const f32x4*>(
                    x + (size_t)(start + r) * HIDDEN + (size_t)lane * 4));
        }
    }

    #pragma unroll
    for (int off = 32; off > 0; off >>= 1)
        acc += __shfl_xor(acc, off);
    if (lane == 0) smem[LDS_SWEEPS * 64 * HIDDEN + wid] = acc;
    __syncthreads();

    float total = 0.0f;
    #pragma unroll
    for (int k = 0; k < 8; ++k) total += smem[LDS_SWEEPS * 64 * HIDDEN + k];
    const float mean = total / ((float)count * (float)HIDDEN);
    const float rr   = 1.0f / sqrtf(mean + EPS);

    const f32x4 wv = *reinterpret_cast<const f32x4*>(w + (size_t)lane * 4);

    // ---- Phase B (reverse sweep order) ----
    // Unstaged region: NT re-read (L3-recency hits), NT store.
    for (int s = nsweep - 1; s >= STAGE_SWEEPS; --s) {
        const int base = (s << 6) + (wid << 3);
        if (base + 8 <= count) {
            f32x4 v[8];
            #pragma unroll
            for (int k = 0; k < 8; ++k)
                v[k] = __builtin_nontemporal_load(reinterpret_cast<const f32x4*>(
                    x + (size_t)(start + base + k) * HIDDEN + (size_t)lane * 4));
            #pragma unroll
            for (int k = 0; k < 8; ++k) {
                f32x4 o = { v[k].x * wv.x * rr, v[k].y * wv.y * rr,
                            v[k].z * wv.z * rr, v[k].w * wv.w * rr };
                __builtin_nontemporal_store(o, reinterpret_cast<f32x4*>(
                    out + (size_t)(start + base + k) * HIDDEN + (size_t)lane * 4));
            }
        } else {
            for (int r = base; r < count; ++r) {
                const f32x4 v = __builtin_nontemporal_load(reinterpret_cast<const f32x4*>(
                    x + (size_t)(start + r) * HIDDEN + (size_t)lane * 4));
                f32x4 o = { v.x * wv.x * rr, v.y * wv.y * rr,
                            v.z * wv.z * rr, v.w * wv.w * rr };
                __builtin_nontemporal_store(o, reinterpret_cast<f32x4*>(
                    out + (size_t)(start + r) * HIDDEN + (size_t)lane * 4));
            }
        }
    }
    // Register-staged region (reversed; static indices).
    #pragma unroll
    for (int j = REG_SWEEPS - 1; j >= 0; --j) {
        const int base = ((LDS_SWEEPS + j) << 6) + (wid << 3);
        if (base + 8 <= count) {
            #pragma unroll
            for (int k = 0; k < 8; ++k) {
                f32x4 o = { rv[j][k].x * wv.x * rr, rv[j][k].y * wv.y * rr,
                            rv[j][k].z * wv.z * rr, rv[j][k].w * wv.w * rr };
                __builtin_nontemporal_store(o, reinterpret_cast<f32x4*>(
                    out + (size_t)(start + base + k) * HIDDEN + (size_t)lane * 4));
            }
        } else {
            for (int r = base; r < count; ++r) {
                const f32x4 v = __builtin_nontemporal_load(reinterpret_cast<const f32x4*>(
                    x + (size_t)(start + r) * HIDDEN + (size_t)lane * 4));
                f32x4 o = { v.x * wv.x * rr, v.y * wv.y * rr,
                            v.z * wv.z * rr, v.w * wv.w * rr };
                __builtin_nontemporal_store(o, reinterpret_cast<f32x4*>(
                    out + (size_t)(start + r) * HIDDEN + (size_t)lane * 4));
            }
        }
    }
    // LDS-staged region.
    #pragma unroll
    for (int s = LDS_SWEEPS - 1; s >= 0; --s) {
        const int base = (s << 6) + (wid << 3);
        if (base + 8 <= count) {
            #pragma unroll
            for (int k = 0; k < 8; ++k) {
                const f32x4 v = *reinterpret_cast<const f32x4*>(
                    &smem[(base + k) * HIDDEN + lane * 4]);
                f32x4 o = { v.x * wv.x * rr, v.y * wv.y * rr,
                            v.z * wv.z * rr, v.w * wv.w * rr };
                __builtin_nontemporal_store(o, reinterpret_cast<f32x4*>(
                    out + (size_t)(start + base + k) * HIDDEN + (size_t)lane * 4));
            }
        } else {
            for (int r = base; r < count; ++r) {
                const f32x4 v = __builtin_nontemporal_load(reinterpret_cast<const f32x4*>(
                    x + (size_t)(start + r) * HIDDEN + (size_t)lane * 4));
                f32x4 o = { v.x * wv.x * rr, v.y * wv.y * rr,
                            v.z * wv.z * rr, v.w * wv.w * rr };
                __builtin_nontemporal_store(o, reinterpret_cast<f32x4*>(
                    out + (size_t)(start + r) * HIDDEN + (size_t)lane * 4));
            }
        }
    }
}

extern "C" void kernel_launch(void* const* d_in, const int* in_sizes, int n_in,
                              void* d_out, int out_size, void* d_ws, size_t ws_size,
                              hipStream_t stream) {
    const float* x     = (const float*)d_in[0];
    const int*   batch = (const int*)d_in[1];
    const float* w     = (const float*)d_in[2];
    float*       out   = (float*)d_out;
    const int n_nodes  = in_sizes[1];

    // One block per graph; 512 threads = 8 waves; 128 KB LDS -> 1 block/CU.
    k_fused<<<NGRAPH, 512, 0, stream>>>(x, batch, w, out, n_nodes);
}

// Round 9
// 457.255 us; speedup vs baseline: 1.0975x; 1.0975x over previous
//
#include <hip/hip_runtime.h>

#define HIDDEN 256
#define NGRAPH 1024
#define EPS 1e-6f
#define LDS_SWEEPS 2          // sweeps staged in LDS   (rows 0..127, 128 KB)
#define REG_SWEEPS 4          // sweeps staged in VGPRs (rows 128..383, 128 VGPR/wave)
#define STAGE_SWEEPS (LDS_SWEEPS + REG_SWEEPS)

typedef float f32x4 __attribute__((ext_vector_type(4)));

__device__ __forceinline__ float ssum(const f32x4 v) {
    return v.x * v.x + v.y * v.y + v.z * v.z + v.w * v.w;
}

// One block per graph (batch sorted => graph g owns contiguous rows [start,end)).
// Phase A: stream the slab once. Rows 0..127 -> LDS, rows 128..383 -> registers
//          (both loaded NON-TEMPORALLY: they never need L3). Rows 384+ loaded
//          cacheable - the only L3-allocating stream, so each line's reuse
//          window fits the 256 MB L3.
// Phase B: reverse sweep order (best-recency lines first). Staged rows come
//          from LDS/VGPRs; the rest via NT loads (dead after use). All output
//          written with NT stores so the 1 GB write stream evicts nothing.
//
// VGPR budget (the r8 lesson): 512-thread block = 2 waves/SIMD mandatory =
// 256 VGPR cap. Peak live = rv 128 + v[] 32 + o temps 32 + misc ~25 < 256.
// 128 KB static LDS forces 1 block/CU: 256 resident blocks x ~1 MB slab ~= L3.
__global__ __launch_bounds__(512, 2) void k_fused(
    const float* __restrict__ x, const int* __restrict__ batch,
    const float* __restrict__ w, float* __restrict__ out, int n_nodes) {

    __shared__ float smem[LDS_SWEEPS * 64 * HIDDEN + 8];   // 128 KB + reduce scratch

    const int g    = (int)blockIdx.x;
    const int tid  = (int)threadIdx.x;
    const int lane = tid & 63;
    const int wid  = tid >> 6;      // 0..7

    // Binary-search graph bounds (wave-uniform broadcast loads, ~40 total).
    int lo = 0, hi = n_nodes;
    while (lo < hi) { int m = (lo + hi) >> 1; if (batch[m] < g) lo = m + 1; else hi = m; }
    const int start = lo;
    int lo2 = start, hi2 = n_nodes;
    while (lo2 < hi2) { int m = (lo2 + hi2) >> 1; if (batch[m] < g + 1) lo2 = m + 1; else hi2 = m; }
    const int count = lo2 - start;
    if (count <= 0) return;         // block-uniform: safe w.r.t. __syncthreads below

    const int nsweep = (count + 63) >> 6;   // 8 waves x 8 rows per sweep

    float acc = 0.0f;
    f32x4 rv[REG_SWEEPS][8];        // statically indexed only (full unroll below)

    // ---- Phase A ----
    // LDS-staged sweeps (NT loads: these lines never need L3).
    #pragma unroll
    for (int s = 0; s < LDS_SWEEPS; ++s) {
        const int base = (s << 6) + (wid << 3);
        if (base + 8 <= count) {
            f32x4 v[8];
            #pragma unroll
            for (int k = 0; k < 8; ++k)
                v[k] = __builtin_nontemporal_load(reinterpret_cast<const f32x4*>(
                    x + (size_t)(start + base + k) * HIDDEN + (size_t)lane * 4));
            #pragma unroll
            for (int k = 0; k < 8; ++k)
                *reinterpret_cast<f32x4*>(&smem[(base + k) * HIDDEN + lane * 4]) = v[k];
            #pragma unroll
            for (int k = 0; k < 8; ++k) acc += ssum(v[k]);
        } else {
            for (int r = base; r < count; ++r)
                acc += ssum(*reinterpret_cast<const f32x4*>(
                    x + (size_t)(start + r) * HIDDEN + (size_t)lane * 4));
        }
    }
    // Register-staged sweeps (NT loads; rv indices compile-time via unroll).
    #pragma unroll
    for (int j = 0; j < REG_SWEEPS; ++j) {
        const int base = ((LDS_SWEEPS + j) << 6) + (wid << 3);
        if (base + 8 <= count) {
            #pragma unroll
            for (int k = 0; k < 8; ++k)
                rv[j][k] = __builtin_nontemporal_load(reinterpret_cast<const f32x4*>(
                    x + (size_t)(start + base + k) * HIDDEN + (size_t)lane * 4));
            #pragma unroll
            for (int k = 0; k < 8; ++k) acc += ssum(rv[j][k]);
        } else {
            for (int r = base; r < count; ++r)
                acc += ssum(*reinterpret_cast<const f32x4*>(
                    x + (size_t)(start + r) * HIDDEN + (size_t)lane * 4));
        }
    }
    // Unstaged sweeps: cacheable loads (the only L3-allocating stream).
    for (int s = STAGE_SWEEPS; s < nsweep; ++s) {
        const int base = (s << 6) + (wid << 3);
        if (base + 8 <= count) {
            f32x4 v[8];
            #pragma unroll
            for (int k = 0; k < 8; ++k)
                v[k] = *reinterpret_cast<const f32x4*>(
                    x + (size_t)(start + base + k) * HIDDEN + (size_t)lane * 4);
            #pragma unroll
            for (int k = 0; k < 8; ++k) acc += ssum(v[k]);
        } else {
            for (int r = base; r < count; ++r)
                acc += ssum(*reinterpret_cast<const f32x4*>(
                    x + (size_t)(start + r) * HIDDEN + (size_t)lane * 4));
        }
    }

    #pragma unroll
    for (int off = 32; off > 0; off >>= 1)
        acc += __shfl_xor(acc, off);
    if (lane == 0) smem[LDS_SWEEPS * 64 * HIDDEN + wid] = acc;
    __syncthreads();

    float total = 0.0f;
    #pragma unroll
    for (int k = 0; k < 8; ++k) total += smem[LDS_SWEEPS * 64 * HIDDEN + k];
    const float mean = total / ((float)count * (float)HIDDEN);
    const float rr   = 1.0f / sqrtf(mean + EPS);

    const f32x4 wv = *reinterpret_cast<const f32x4*>(w + (size_t)lane * 4);

    // ---- Phase B (reverse sweep order) ----
    // Unstaged region: NT re-read (L3-recency hits), NT store.
    for (int s = nsweep - 1; s >= STAGE_SWEEPS; --s) {
        const int base = (s << 6) + (wid << 3);
        if (base + 8 <= count) {
            f32x4 v[8];
            #pragma unroll
            for (int k = 0; k < 8; ++k)
                v[k] = __builtin_nontemporal_load(reinterpret_cast<const f32x4*>(
                    x + (size_t)(start + base + k) * HIDDEN + (size_t)lane * 4));
            #pragma unroll
            for (int k = 0; k < 8; ++k) {
                f32x4 o = { v[k].x * wv.x * rr, v[k].y * wv.y * rr,
                            v[k].z * wv.z * rr, v[k].w * wv.w * rr };
                __builtin_nontemporal_store(o, reinterpret_cast<f32x4*>(
                    out + (size_t)(start + base + k) * HIDDEN + (size_t)lane * 4));
            }
        } else {
            for (int r = base; r < count; ++r) {
                const f32x4 v = __builtin_nontemporal_load(reinterpret_cast<const f32x4*>(
                    x + (size_t)(start + r) * HIDDEN + (size_t)lane * 4));
                f32x4 o = { v.x * wv.x * rr, v.y * wv.y * rr,
                            v.z * wv.z * rr, v.w * wv.w * rr };
                __builtin_nontemporal_store(o, reinterpret_cast<f32x4*>(
                    out + (size_t)(start + r) * HIDDEN + (size_t)lane * 4));
            }
        }
    }
    // Register-staged region (reversed; static indices).
    #pragma unroll
    for (int j = REG_SWEEPS - 1; j >= 0; --j) {
        const int base = ((LDS_SWEEPS + j) << 6) + (wid << 3);
        if (base + 8 <= count) {
            #pragma unroll
            for (int k = 0; k < 8; ++k) {
                f32x4 o = { rv[j][k].x * wv.x * rr, rv[j][k].y * wv.y * rr,
                            rv[j][k].z * wv.z * rr, rv[j][k].w * wv.w * rr };
                __builtin_nontemporal_store(o, reinterpret_cast<f32x4*>(
                    out + (size_t)(start + base + k) * HIDDEN + (size_t)lane * 4));
            }
        } else {
            for (int r = base; r < count; ++r) {
                const f32x4 v = __builtin_nontemporal_load(reinterpret_cast<const f32x4*>(
                    x + (size_t)(start + r) * HIDDEN + (size_t)lane * 4));
                f32x4 o = { v.x * wv.x * rr, v.y * wv.y * rr,
                            v.z * wv.z * rr, v.w * wv.w * rr };
                __builtin_nontemporal_store(o, reinterpret_cast<f32x4*>(
                    out + (size_t)(start + r) * HIDDEN + (size_t)lane * 4));
            }
        }
    }
    // LDS-staged region.
    #pragma unroll
    for (int s = LDS_SWEEPS - 1; s >= 0; --s) {
        const int base = (s << 6) + (wid << 3);
        if (base + 8 <= count) {
            #pragma unroll
            for (int k = 0; k < 8; ++k) {
                const f32x4 v = *reinterpret_cast<const f32x4*>(
                    &smem[(base + k) * HIDDEN + lane * 4]);
                f32x4 o = { v.x * wv.x * rr, v.y * wv.y * rr,
                            v.z * wv.z * rr, v.w * wv.w * rr };
                __builtin_nontemporal_store(o, reinterpret_cast<f32x4*>(
                    out + (size_t)(start + base + k) * HIDDEN + (size_t)lane * 4));
            }
        } else {
            for (int r = base; r < count; ++r) {
                const f32x4 v = __builtin_nontemporal_load(reinterpret_cast<const f32x4*>(
                    x + (size_t)(start + r) * HIDDEN + (size_t)lane * 4));
                f32x4 o = { v.x * wv.x * rr, v.y * wv.y * rr,
                            v.z * wv.z * rr, v.w * wv.w * rr };
                __builtin_nontemporal_store(o, reinterpret_cast<f32x4*>(
                    out + (size_t)(start + r) * HIDDEN + (size_t)lane * 4));
            }
        }
    }
}

extern "C" void kernel_launch(void* const* d_in, const int* in_sizes, int n_in,
                              void* d_out, int out_size, void* d_ws, size_t ws_size,
                              hipStream_t stream) {
    const float* x     = (const float*)d_in[0];
    const int*   batch = (const int*)d_in[1];
    const float* w     = (const float*)d_in[2];
    float*       out   = (float*)d_out;
    const int n_nodes  = in_sizes[1];

    // One block per graph; 512 threads = 8 waves; 128 KB LDS -> 1 block/CU.
    k_fused<<<NGRAPH, 512, 0, stream>>>(x, batch, w, out, n_nodes);
}

// Round 10
// 431.847 us; speedup vs baseline: 1.1621x; 1.0588x over previous
//
#include <hip/hip_runtime.h>

#define HIDDEN 256
#define NGRAPH 1024
#define EPS 1e-6f
#define STAGE_ROWS 152    // slab head staged in LDS (152 KB)
#define CACHE_SWEEPS 8    // last 512 rows per slab load cacheable (~131 MB aggregate)

typedef float f32x4 __attribute__((ext_vector_type(4)));

__device__ __forceinline__ float ssum(const f32x4 v) {
    return v.x * v.x + v.y * v.y + v.z * v.z + v.w * v.w;
}

// One block per graph (batch sorted => graph g owns contiguous rows [start,end)).
//
// Explicit cache-policy windowing (r10): phase A loads are
//   rows 0..151          : NT load -> LDS stage (never needed from memory again)
//   middle rows          : NT load (conceded as guaranteed phase-B misses;
//                          keeps them OUT of L3 so they don't churn the window)
//   last 512 rows        : cacheable — the only L3-allocating stream.
//                          512 rows x 1 KB x 256 resident blocks ~= 131 MB,
//                          fits the 256 MB L3 with 2x margin even if the
//                          NT write stream still allocates.
// Phase B (reverse sweep order): tail from L3 (hits), middle via NT (HBM),
// head from LDS. All output via NT stores.
//
// 152 KB static LDS forces 1 block/CU (256 resident blocks).
__global__ __launch_bounds__(512) void k_fused(
    const float* __restrict__ x, const int* __restrict__ batch,
    const float* __restrict__ w, float* __restrict__ out, int n_nodes) {

    __shared__ float smem[STAGE_ROWS * HIDDEN + 8];   // 152 KB stage + reduce scratch

    const int g    = (int)blockIdx.x;
    const int tid  = (int)threadIdx.x;
    const int lane = tid & 63;
    const int wid  = tid >> 6;      // 0..7

    // Binary-search graph bounds (wave-uniform broadcast loads, ~40 total).
    int lo = 0, hi = n_nodes;
    while (lo < hi) { int m = (lo + hi) >> 1; if (batch[m] < g) lo = m + 1; else hi = m; }
    const int start = lo;
    int lo2 = start, hi2 = n_nodes;
    while (lo2 < hi2) { int m = (lo2 + hi2) >> 1; if (batch[m] < g + 1) lo2 = m + 1; else hi2 = m; }
    const int count = lo2 - start;
    if (count <= 0) return;         // block-uniform: safe w.r.t. __syncthreads below

    const int nsweep     = (count + 63) >> 6;   // 8 waves x 8 rows per sweep
    const int cache_from = (nsweep > CACHE_SWEEPS) ? (nsweep - CACHE_SWEEPS) : 0;

    // ---- Phase A: sum of squares, explicit per-region cache policy ----
    float acc = 0.0f;
    for (int s = 0; s < nsweep; ++s) {
        const int base = (s << 6) + (wid << 3);
        if (base + 8 <= count) {
            f32x4 v[8];
            if (base + 8 <= STAGE_ROWS) {
                // Head: NT load + LDS stage.
                #pragma unroll
                for (int k = 0; k < 8; ++k)
                    v[k] = __builtin_nontemporal_load(reinterpret_cast<const f32x4*>(
                        x + (size_t)(start + base + k) * HIDDEN + (size_t)lane * 4));
                #pragma unroll
                for (int k = 0; k < 8; ++k)
                    *reinterpret_cast<f32x4*>(&smem[(base + k) * HIDDEN + lane * 4]) = v[k];
            } else if (s < cache_from) {
                // Middle: NT load, no L3 allocation.
                #pragma unroll
                for (int k = 0; k < 8; ++k)
                    v[k] = __builtin_nontemporal_load(reinterpret_cast<const f32x4*>(
                        x + (size_t)(start + base + k) * HIDDEN + (size_t)lane * 4));
            } else {
                // Tail window: cacheable (the only L3-allocating stream).
                #pragma unroll
                for (int k = 0; k < 8; ++k)
                    v[k] = *reinterpret_cast<const f32x4*>(
                        x + (size_t)(start + base + k) * HIDDEN + (size_t)lane * 4);
            }
            #pragma unroll
            for (int k = 0; k < 8; ++k) acc += ssum(v[k]);
        } else {
            for (int r = base; r < count; ++r)
                acc += ssum(*reinterpret_cast<const f32x4*>(
                    x + (size_t)(start + r) * HIDDEN + (size_t)lane * 4));
        }
    }
    #pragma unroll
    for (int off = 32; off > 0; off >>= 1)
        acc += __shfl_xor(acc, off);
    if (lane == 0) smem[STAGE_ROWS * HIDDEN + wid] = acc;
    __syncthreads();

    float total = 0.0f;
    #pragma unroll
    for (int k = 0; k < 8; ++k) total += smem[STAGE_ROWS * HIDDEN + k];
    const float mean = total / ((float)count * (float)HIDDEN);
    const float rr   = 1.0f / sqrtf(mean + EPS);

    // ---- Phase B: normalize; reverse sweep order; LDS head + NT loads; NT stores ----
    const f32x4 wv = *reinterpret_cast<const f32x4*>(w + (size_t)lane * 4);
    for (int s = nsweep - 1; s >= 0; --s) {
        const int base = (s << 6) + (wid << 3);
        if (base + 8 <= count) {
            f32x4 v[8];
            if (base + 8 <= STAGE_ROWS) {   // staged in phase A by THIS wave
                #pragma unroll
                for (int k = 0; k < 8; ++k)
                    v[k] = *reinterpret_cast<const f32x4*>(
                        &smem[(base + k) * HIDDEN + lane * 4]);
            } else {
                #pragma unroll
                for (int k = 0; k < 8; ++k)
                    v[k] = __builtin_nontemporal_load(reinterpret_cast<const f32x4*>(
                        x + (size_t)(start + base + k) * HIDDEN + (size_t)lane * 4));
            }
            #pragma unroll
            for (int k = 0; k < 8; ++k) {
                f32x4 o = { v[k].x * wv.x * rr, v[k].y * wv.y * rr,
                            v[k].z * wv.z * rr, v[k].w * wv.w * rr };
                __builtin_nontemporal_store(o, reinterpret_cast<f32x4*>(
                    out + (size_t)(start + base + k) * HIDDEN + (size_t)lane * 4));
            }
        } else {
            for (int r = base; r < count; ++r) {
                const f32x4 v = __builtin_nontemporal_load(reinterpret_cast<const f32x4*>(
                    x + (size_t)(start + r) * HIDDEN + (size_t)lane * 4));
                f32x4 o = { v.x * wv.x * rr, v.y * wv.y * rr,
                            v.z * wv.z * rr, v.w * wv.w * rr };
                __builtin_nontemporal_store(o, reinterpret_cast<f32x4*>(
                    out + (size_t)(start + r) * HIDDEN + (size_t)lane * 4));
            }
        }
    }
}

extern "C" void kernel_launch(void* const* d_in, const int* in_sizes, int n_in,
                              void* d_out, int out_size, void* d_ws, size_t ws_size,
                              hipStream_t stream) {
    const float* x     = (const float*)d_in[0];
    const int*   batch = (const int*)d_in[1];
    const float* w     = (const float*)d_in[2];
    float*       out   = (float*)d_out;
    const int n_nodes  = in_sizes[1];

    // One block per graph; 512 threads = 8 waves; 152 KB LDS -> 1 block/CU.
    k_fused<<<NGRAPH, 512, 0, stream>>>(x, batch, w, out, n_nodes);
}